// Round 8
// baseline (654.812 us; speedup 1.0000x reference)
//
#include <hip/hip_runtime.h>
#include <hip/hip_bf16.h>

// DiagonalWindowAttention (v6: split attention/projection for occupancy).
//   build_comb : comb[mi][n][q][k] = mask + rel-pos bias (d_ws)
//   dwa_attn   : per window (2048 blocks, 256 thr, LDS 24.6 KB, LB(256,5)):
//                LN stats -> per-head {stage Q/K/VT from prefetched packed regs,
//                QK^T MFMA (C=comb), softmax, PV MFMA, pre -> d_ws bf16}
//   dwa_proj   : per window: pre[256][96] @ W^T + bias, inverse grouping store
//   fallback   : r7 fused kernel when ws_size is too small for comb+pre
//
// token grouping: p = wh*8+ww, s = sh*2+sw, seq g = wh*32+sh*16+ww*2+sw

#define TPB 256

// LDS byte offsets (attn kernel)
#define Q0   0        // [64][64] bf16 swizzled (8 KB); P overlays after QK^T
#define K0   8192
#define VT0  16384    // V^T per head (8 KB)
#define ATTN_LDS 24576

typedef __attribute__((ext_vector_type(8))) short short8;
typedef __attribute__((ext_vector_type(4))) float f32x4;

union FRAG { uint4 u4; short8 s8; unsigned short us[8]; };

__device__ __forceinline__ int seq_of(int p, int s) {
    return ((p >> 3) << 5) | ((s >> 1) << 4) | ((p & 7) << 1) | (s & 1);
}

#define SWZ(row, slot) (((row) << 7) + ((((slot) ^ ((row) & 7))) << 4))

#define LGKM_FENCE() do { \
    asm volatile("s_waitcnt lgkmcnt(0)" ::: "memory"); \
    __builtin_amdgcn_sched_barrier(0); } while (0)

// stage-complete barrier: drain LDS writes, sync; vmcnt stays in flight
#define BAR_STAGE() do { \
    asm volatile("s_waitcnt lgkmcnt(0)" ::: "memory"); \
    __builtin_amdgcn_sched_barrier(0); \
    __builtin_amdgcn_s_barrier(); \
    __builtin_amdgcn_sched_barrier(0); } while (0)

// WAR barrier: all my LDS reads already retired via data deps
#define BAR_WAR() do { \
    __builtin_amdgcn_sched_barrier(0); \
    __builtin_amdgcn_s_barrier(); \
    __builtin_amdgcn_sched_barrier(0); } while (0)

__device__ __forceinline__ unsigned short f2b(float x) {
    union { __hip_bfloat16 h; unsigned short u; } z;
    z.h = __float2bfloat16(x);
    return z.u;
}

__device__ __forceinline__ uint4 pack8(const float* v) {
    union { uint4 u4; unsigned short us[8]; } z;
#pragma unroll
    for (int i = 0; i < 8; ++i) z.us[i] = f2b(v[i]);
    return z.u4;
}

__device__ __forceinline__ void load_pack(const float* src, uint4* dst) {
    float v[16];
#pragma unroll
    for (int i = 0; i < 4; ++i) {
        float4 x = ((const float4*)src)[i];
        v[4 * i] = x.x; v[4 * i + 1] = x.y; v[4 * i + 2] = x.z; v[4 * i + 3] = x.w;
    }
    dst[0] = pack8(v);
    dst[1] = pack8(v + 8);
}

__device__ __forceinline__ void load_pack_qln(const float* src, const float* ga,
                                              const float* be, float mu, float rs,
                                              uint4* dst) {
    float v[16];
#pragma unroll
    for (int i = 0; i < 4; ++i) {
        float4 x = ((const float4*)src)[i];
        float4 g = ((const float4*)ga)[i];
        float4 b = ((const float4*)be)[i];
        v[4 * i + 0] = ((x.x - mu) * rs * g.x + b.x) * 0.125f;
        v[4 * i + 1] = ((x.y - mu) * rs * g.y + b.y) * 0.125f;
        v[4 * i + 2] = ((x.z - mu) * rs * g.z + b.z) * 0.125f;
        v[4 * i + 3] = ((x.w - mu) * rs * g.w + b.w) * 0.125f;
    }
    dst[0] = pack8(v);
    dst[1] = pack8(v + 8);
}

// ---------------- pre-kernel: comb = mask + rel-pos bias ----------------
__global__ void build_comb(const float* __restrict__ gmask,
                           const float* __restrict__ gbt,
                           float* __restrict__ comb) {
    const int b = blockIdx.x;            // b = mi*6 + n
    const int mi = b / 6, n = b - mi * 6;
    const int t = threadIdx.x;
    const float* mrow = gmask + (size_t)mi * 4096;
    float* crow = comb + (size_t)b * 4096;
#pragma unroll
    for (int e = 0; e < 4096; e += TPB) {
        const int i = e + t;
        const int q = i >> 6, k = i & 63;
        const int idx = ((q >> 3) - (k >> 3) + 7) * 15 + ((q & 7) - (k & 7) + 7);
        crow[i] = mrow[i] + gbt[idx * 6 + n];
    }
}

// ======================= split path: attention kernel =======================
__global__ __launch_bounds__(TPB, 5)
void dwa_attn(const float* __restrict__ gq,
              const float* __restrict__ gk,
              const float* __restrict__ gv,
              const float* __restrict__ ggamma,
              const float* __restrict__ gbeta,
              const float* __restrict__ comb,
              __hip_bfloat16* __restrict__ gpre,
              int nwm)
{
    __shared__ __align__(16) unsigned char Lraw[ATTN_LDS];
    char* L = (char*)Lraw;

    const int w = blockIdx.x;
    const int t = threadIdx.x;
    const int lane = t & 63, wv = t >> 6;
    const int r15 = lane & 15, gsl = lane >> 4;

    const int p_a = t >> 2, s_a = t & 3;
    const int g_a = seq_of(p_a, s_a);
    const size_t rowbase = ((size_t)w * 256 + g_a) * 96;
    const int qr0 = (wv << 4) + (gsl << 2);
    const f32x4 zf = {0.f, 0.f, 0.f, 0.f};

    // LN stats (registers only)
    float mu, rs;
    {
        const float4* qr4 = (const float4*)(gq + rowbase);
        float sum = 0.f, ssq = 0.f;
#pragma unroll
        for (int i = 0; i < 24; ++i) {
            float4 x = qr4[i];
            sum += (x.x + x.y) + (x.z + x.w);
            ssq += (x.x * x.x + x.y * x.y) + (x.z * x.z + x.w * x.w);
        }
        sum += __shfl_xor(sum, 1); ssq += __shfl_xor(ssq, 1);
        sum += __shfl_xor(sum, 2); ssq += __shfl_xor(ssq, 2);
        mu = sum * (1.f / 384.f);
        rs = rsqrtf(ssq * (1.f / 384.f) - mu * mu + 1e-5f);
    }
    const float* gaT = ggamma + s_a * 96;
    const float* beT = gbeta + s_a * 96;

    // prefetch head 0 (packed bf16 in regs)
    uint4 qpf[2][2], kpf[2][2], vpf[2][2];
    load_pack_qln(gq + rowbase, gaT, beT, mu, rs, qpf[0]);
    load_pack(gk + rowbase, kpf[0]);
    load_pack(gv + rowbase, vpf[0]);

#pragma unroll
    for (int n = 0; n < 6; ++n) {
        // stage Q/K (row-major swz) + VT (transposed) from packed regs
        *(uint4*)(L + Q0 + SWZ(p_a, s_a * 2))     = qpf[n & 1][0];
        *(uint4*)(L + Q0 + SWZ(p_a, s_a * 2 + 1)) = qpf[n & 1][1];
        *(uint4*)(L + K0 + SWZ(p_a, s_a * 2))     = kpf[n & 1][0];
        *(uint4*)(L + K0 + SWZ(p_a, s_a * 2 + 1)) = kpf[n & 1][1];
#pragma unroll
        for (int h = 0; h < 2; ++h) {
            FRAG u; u.u4 = vpf[n & 1][h];
#pragma unroll
            for (int c = 0; c < 8; ++c) {
                const int np_ = s_a * 16 + h * 8 + c;
                *(unsigned short*)(L + VT0 + (np_ << 7) +
                    ((((p_a >> 3) ^ (np_ & 7))) << 4) + ((p_a & 7) << 1)) = u.us[c];
            }
        }
        // prefetch next head (stays in flight across the barrier)
        if (n < 5) {
            const int off = (n + 1) * 16;
            load_pack_qln(gq + rowbase + off, gaT + off, beT + off, mu, rs,
                          qpf[(n + 1) & 1]);
            load_pack(gk + rowbase + off, kpf[(n + 1) & 1]);
            load_pack(gv + rowbase + off, vpf[(n + 1) & 1]);
        }
        // C init = comb (bias+mask)
        f32x4 sacc[4];
        {
            const float* cb = comb + (size_t)((w % nwm) * 6 + n) * 4096;
#pragma unroll
            for (int tile = 0; tile < 4; ++tile)
#pragma unroll
                for (int r = 0; r < 4; ++r)
                    sacc[tile][r] = cb[((qr0 + r) << 6) + (tile << 4) + r15];
        }
        BAR_STAGE();

        // QK^T
        {
            FRAG a0, a1;
            a0.u4 = *(const uint4*)(L + Q0 + SWZ(wv * 16 + r15, gsl));
            a1.u4 = *(const uint4*)(L + Q0 + SWZ(wv * 16 + r15, 4 + gsl));
#pragma unroll
            for (int tile = 0; tile < 4; ++tile) {
                FRAG b0, b1;
                b0.u4 = *(const uint4*)(L + K0 + SWZ(tile * 16 + r15, gsl));
                b1.u4 = *(const uint4*)(L + K0 + SWZ(tile * 16 + r15, 4 + gsl));
                sacc[tile] = __builtin_amdgcn_mfma_f32_16x16x32_bf16(a0.s8, b0.s8, sacc[tile], 0, 0, 0);
                sacc[tile] = __builtin_amdgcn_mfma_f32_16x16x32_bf16(a1.s8, b1.s8, sacc[tile], 0, 0, 0);
            }
        }

        // softmax; P overlays Q0 (wave-private rows)
#pragma unroll
        for (int r = 0; r < 4; ++r) {
            const int q = qr0 + r;
            float mx = fmaxf(fmaxf(sacc[0][r], sacc[1][r]),
                             fmaxf(sacc[2][r], sacc[3][r]));
            mx = fmaxf(mx, __shfl_xor(mx, 1));
            mx = fmaxf(mx, __shfl_xor(mx, 2));
            mx = fmaxf(mx, __shfl_xor(mx, 4));
            mx = fmaxf(mx, __shfl_xor(mx, 8));
            float sm = 0.f;
#pragma unroll
            for (int tile = 0; tile < 4; ++tile) {
                sacc[tile][r] = __expf(sacc[tile][r] - mx);
                sm += sacc[tile][r];
            }
            sm += __shfl_xor(sm, 1);
            sm += __shfl_xor(sm, 2);
            sm += __shfl_xor(sm, 4);
            sm += __shfl_xor(sm, 8);
            const float inv = 1.0f / sm;
#pragma unroll
            for (int tile = 0; tile < 4; ++tile) {
                const int col = (tile << 4) + r15;
                *(unsigned short*)(L + Q0 + (q << 7) +
                                   (((col >> 3) ^ (q & 7)) << 4) + ((col & 7) << 1))
                    = f2b(sacc[tile][r] * inv);
            }
        }
        LGKM_FENCE();

        // PV
        f32x4 oacc[4];
        {
            FRAG pa0, pa1;
            pa0.u4 = *(const uint4*)(L + Q0 + SWZ(wv * 16 + r15, gsl));
            pa1.u4 = *(const uint4*)(L + Q0 + SWZ(wv * 16 + r15, 4 + gsl));
#pragma unroll
            for (int ct = 0; ct < 4; ++ct) {
                FRAG b0, b1;
                b0.u4 = *(const uint4*)(L + VT0 + SWZ(ct * 16 + r15, gsl));
                b1.u4 = *(const uint4*)(L + VT0 + SWZ(ct * 16 + r15, 4 + gsl));
                oacc[ct] = __builtin_amdgcn_mfma_f32_16x16x32_bf16(pa0.s8, b0.s8, zf, 0, 0, 0);
                oacc[ct] = __builtin_amdgcn_mfma_f32_16x16x32_bf16(pa1.s8, b1.s8, oacc[ct], 0, 0, 0);
            }
        }

        // pre[w][n][tok][16] bf16 -> d_ws (fire-and-forget stores)
        {
            __hip_bfloat16* pb = gpre + (((size_t)w * 6 + n) << 12) + r15;
#pragma unroll
            for (int ct = 0; ct < 4; ++ct)
#pragma unroll
                for (int r = 0; r < 4; ++r) {
                    const int tok = ((qr0 + r) << 2) + ct;
                    union { __hip_bfloat16 h; unsigned short u; } z;
                    z.u = f2b(oacc[ct][r]);
                    pb[tok << 4] = z.h;
                }
        }
        BAR_WAR();
    }
}

// ======================= split path: projection kernel =======================
__global__ __launch_bounds__(TPB, 4)
void dwa_proj(const __hip_bfloat16* __restrict__ gpre,
              const float* __restrict__ gpw,
              const float* __restrict__ gpb,
              float* __restrict__ gout)
{
    const int w = blockIdx.x;
    const int t = threadIdx.x;
    const int lane = t & 63, wv = t >> 6;
    const int r15 = lane & 15, gsl = lane >> 4;
    const f32x4 zf = {0.f, 0.f, 0.f, 0.f};

    // W B-frags: o = ct*16 + r15, k-slice = kk*32 + gsl*8
    FRAG bw[3][6];
#pragma unroll
    for (int kk = 0; kk < 3; ++kk)
#pragma unroll
        for (int ct = 0; ct < 6; ++ct) {
            const int o = (ct << 4) + r15;
            const float4* wp = (const float4*)(gpw + o * 96 + kk * 32 + (gsl << 3));
            float4 w0 = wp[0], w1 = wp[1];
            float w8[8] = {w0.x, w0.y, w0.z, w0.w, w1.x, w1.y, w1.z, w1.w};
            bw[kk][ct].u4 = pack8(w8);
        }
    float pbv[6];
#pragma unroll
    for (int ct = 0; ct < 6; ++ct) pbv[ct] = gpb[(ct << 4) + r15];

#pragma unroll
    for (int mt = 0; mt < 4; ++mt) {
        const int rowA = (wv << 6) + (mt << 4) + r15;
        FRAG A[3];
#pragma unroll
        for (int kk = 0; kk < 3; ++kk) {
            const int n = kk * 2 + (gsl >> 1);
            const int c0 = (gsl & 1) << 3;
            A[kk].u4 = *(const uint4*)(gpre + (((size_t)w * 6 + n) << 12) +
                                       (rowA << 4) + c0);
        }
        f32x4 acc[6];
#pragma unroll
        for (int ct = 0; ct < 6; ++ct) {
            acc[ct] = __builtin_amdgcn_mfma_f32_16x16x32_bf16(A[0].s8, bw[0][ct].s8, zf, 0, 0, 0);
            acc[ct] = __builtin_amdgcn_mfma_f32_16x16x32_bf16(A[1].s8, bw[1][ct].s8, acc[ct], 0, 0, 0);
            acc[ct] = __builtin_amdgcn_mfma_f32_16x16x32_bf16(A[2].s8, bw[2][ct].s8, acc[ct], 0, 0, 0);
        }
#pragma unroll
        for (int ct = 0; ct < 6; ++ct)
#pragma unroll
            for (int rr = 0; rr < 4; ++rr) {
                const int token = (wv << 6) + (mt << 4) + (gsl << 2) + rr;
                const int p = token >> 2, s = token & 3;
                const int gsq = seq_of(p, s);
                gout[((size_t)w * 256 + gsq) * 96 + (ct << 4) + r15]
                    = acc[ct][rr] + pbv[ct];
            }
    }
}

// ======================= fallback: r7 fused kernel =======================
#define FQ0   0
#define FK0   8192
#define FVT0  16384
#define FPR0  24576
#define F_LDS 77824

template <int USE_COMB>
__global__ __launch_bounds__(TPB, 2)
void dwa_fused(const float* __restrict__ gq,
               const float* __restrict__ gk,
               const float* __restrict__ gv,
               const float* __restrict__ gmask,
               const float* __restrict__ gbt,
               const float* __restrict__ ggamma,
               const float* __restrict__ gbeta,
               const float* __restrict__ gpw,
               const float* __restrict__ gpb,
               float* __restrict__ gout,
               const float* __restrict__ comb,
               int nwm)
{
    __shared__ __align__(16) unsigned char Lraw[F_LDS];
    char* L = (char*)Lraw;

    const int w = blockIdx.x;
    const int t = threadIdx.x;
    const int lane = t & 63, wv = t >> 6;
    const int r15 = lane & 15, gsl = lane >> 4;

    const int p_a = t >> 2, s_a = t & 3;
    const int g_a = seq_of(p_a, s_a);
    const size_t rowbase = ((size_t)w * 256 + g_a) * 96;
    const int mbase = (w % nwm) * 4096;
    const int qr0 = (wv << 4) + (gsl << 2);
    const f32x4 zf = {0.f, 0.f, 0.f, 0.f};

    uint4 qreg[12];
    {
        float qv[96];
        float sum = 0.f, ssq = 0.f;
        const float4* qr4 = (const float4*)(gq + rowbase);
#pragma unroll
        for (int i = 0; i < 24; ++i) {
            float4 x = qr4[i];
            qv[4 * i] = x.x; qv[4 * i + 1] = x.y;
            qv[4 * i + 2] = x.z; qv[4 * i + 3] = x.w;
            sum += (x.x + x.y) + (x.z + x.w);
            ssq += (x.x * x.x + x.y * x.y) + (x.z * x.z + x.w * x.w);
        }
        sum += __shfl_xor(sum, 1); ssq += __shfl_xor(ssq, 1);
        sum += __shfl_xor(sum, 2); ssq += __shfl_xor(ssq, 2);
        const float mu = sum * (1.f / 384.f);
        const float rs = rsqrtf(ssq * (1.f / 384.f) - mu * mu + 1e-5f);
        const float4* ga4 = (const float4*)(ggamma + s_a * 96);
        const float4* be4 = (const float4*)(gbeta + s_a * 96);
#pragma unroll
        for (int c6 = 0; c6 < 6; ++c6) {
            float vals[16];
#pragma unroll
            for (int j = 0; j < 4; ++j) {
                float4 g = ga4[c6 * 4 + j];
                float4 b = be4[c6 * 4 + j];
                const int base = c6 * 16 + 4 * j;
                vals[4 * j + 0] = ((qv[base + 0] - mu) * rs * g.x + b.x) * 0.125f;
                vals[4 * j + 1] = ((qv[base + 1] - mu) * rs * g.y + b.y) * 0.125f;
                vals[4 * j + 2] = ((qv[base + 2] - mu) * rs * g.z + b.z) * 0.125f;
                vals[4 * j + 3] = ((qv[base + 3] - mu) * rs * g.w + b.w) * 0.125f;
            }
            qreg[2 * c6]     = pack8(vals);
            qreg[2 * c6 + 1] = pack8(vals + 8);
        }
    }
    uint4 kpf[2][2], vpf[2][2];
    load_pack(gk + rowbase, kpf[0]);
    load_pack(gv + rowbase, vpf[0]);

#pragma unroll
    for (int n = 0; n < 6; ++n) {
        *(uint4*)(L + FQ0 + SWZ(p_a, s_a * 2))     = qreg[2 * n];
        *(uint4*)(L + FQ0 + SWZ(p_a, s_a * 2 + 1)) = qreg[2 * n + 1];
        *(uint4*)(L + FK0 + SWZ(p_a, s_a * 2))     = kpf[n & 1][0];
        *(uint4*)(L + FK0 + SWZ(p_a, s_a * 2 + 1)) = kpf[n & 1][1];
#pragma unroll
        for (int h = 0; h < 2; ++h) {
            FRAG u; u.u4 = vpf[n & 1][h];
#pragma unroll
            for (int c = 0; c < 8; ++c) {
                const int np_ = s_a * 16 + h * 8 + c;
                *(unsigned short*)(L + FVT0 + (np_ << 7) +
                    ((((p_a >> 3) ^ (np_ & 7))) << 4) + ((p_a & 7) << 1)) = u.us[c];
            }
        }
        if (n < 5) {
            load_pack(gk + rowbase + (n + 1) * 16, kpf[(n + 1) & 1]);
            load_pack(gv + rowbase + (n + 1) * 16, vpf[(n + 1) & 1]);
        }
        f32x4 sacc[4];
        if (USE_COMB) {
            const float* cb = comb + (size_t)((w % nwm) * 6 + n) * 4096;
#pragma unroll
            for (int tile = 0; tile < 4; ++tile)
#pragma unroll
                for (int r = 0; r < 4; ++r)
                    sacc[tile][r] = cb[((qr0 + r) << 6) + (tile << 4) + r15];
        } else {
#pragma unroll
            for (int tile = 0; tile < 4; ++tile) {
                const int kpx = (tile << 4) + r15;
                const int ik = kpx >> 3, jk = kpx & 7;
#pragma unroll
                for (int r = 0; r < 4; ++r) {
                    const int q = qr0 + r;
                    sacc[tile][r] = gbt[(((q >> 3) - ik + 7) * 15 + ((q & 7) - jk + 7)) * 6 + n]
                                  + gmask[mbase + (q << 6) + kpx];
                }
            }
        }
        __syncthreads();
        {
            FRAG a0, a1;
            a0.u4 = *(const uint4*)(L + FQ0 + SWZ(wv * 16 + r15, gsl));
            a1.u4 = *(const uint4*)(L + FQ0 + SWZ(wv * 16 + r15, 4 + gsl));
#pragma unroll
            for (int tile = 0; tile < 4; ++tile) {
                FRAG b0, b1;
                b0.u4 = *(const uint4*)(L + FK0 + SWZ(tile * 16 + r15, gsl));
                b1.u4 = *(const uint4*)(L + FK0 + SWZ(tile * 16 + r15, 4 + gsl));
                sacc[tile] = __builtin_amdgcn_mfma_f32_16x16x32_bf16(a0.s8, b0.s8, sacc[tile], 0, 0, 0);
                sacc[tile] = __builtin_amdgcn_mfma_f32_16x16x32_bf16(a1.s8, b1.s8, sacc[tile], 0, 0, 0);
            }
        }
#pragma unroll
        for (int r = 0; r < 4; ++r) {
            const int q = qr0 + r;
            float mx = fmaxf(fmaxf(sacc[0][r], sacc[1][r]),
                             fmaxf(sacc[2][r], sacc[3][r]));
            mx = fmaxf(mx, __shfl_xor(mx, 1));
            mx = fmaxf(mx, __shfl_xor(mx, 2));
            mx = fmaxf(mx, __shfl_xor(mx, 4));
            mx = fmaxf(mx, __shfl_xor(mx, 8));
            float sm = 0.f;
#pragma unroll
            for (int tile = 0; tile < 4; ++tile) {
                sacc[tile][r] = __expf(sacc[tile][r] - mx);
                sm += sacc[tile][r];
            }
            sm += __shfl_xor(sm, 1);
            sm += __shfl_xor(sm, 2);
            sm += __shfl_xor(sm, 4);
            sm += __shfl_xor(sm, 8);
            const float inv = 1.0f / sm;
#pragma unroll
            for (int tile = 0; tile < 4; ++tile) {
                const int col = (tile << 4) + r15;
                *(unsigned short*)(L + FQ0 + (q << 7) +
                                   (((col >> 3) ^ (q & 7)) << 4) + ((col & 7) << 1))
                    = f2b(sacc[tile][r] * inv);
            }
        }
        LGKM_FENCE();
        f32x4 oacc[4];
        {
            FRAG pa0, pa1;
            pa0.u4 = *(const uint4*)(L + FQ0 + SWZ(wv * 16 + r15, gsl));
            pa1.u4 = *(const uint4*)(L + FQ0 + SWZ(wv * 16 + r15, 4 + gsl));
#pragma unroll
            for (int ct = 0; ct < 4; ++ct) {
                FRAG b0, b1;
                b0.u4 = *(const uint4*)(L + FVT0 + SWZ(ct * 16 + r15, gsl));
                b1.u4 = *(const uint4*)(L + FVT0 + SWZ(ct * 16 + r15, 4 + gsl));
                oacc[ct] = __builtin_amdgcn_mfma_f32_16x16x32_bf16(pa0.s8, b0.s8, zf, 0, 0, 0);
                oacc[ct] = __builtin_amdgcn_mfma_f32_16x16x32_bf16(pa1.s8, b1.s8, oacc[ct], 0, 0, 0);
            }
        }
#pragma unroll
        for (int ct = 0; ct < 4; ++ct)
#pragma unroll
            for (int r = 0; r < 4; ++r) {
                const int token = ((qr0 + r) << 2) + ct;
                *(unsigned short*)(L + FPR0 + token * 208 + ((n << 4) + r15) * 2)
                    = f2b(oacc[ct][r]);
            }
        __syncthreads();
    }
    {
        FRAG bw[3][6];
#pragma unroll
        for (int kk = 0; kk < 3; ++kk)
#pragma unroll
            for (int ct = 0; ct < 6; ++ct) {
                const int o = (ct << 4) + r15;
                const float4* wp = (const float4*)(gpw + o * 96 + kk * 32 + (gsl << 3));
                float4 w0 = wp[0], w1 = wp[1];
                float w8[8] = {w0.x, w0.y, w0.z, w0.w, w1.x, w1.y, w1.z, w1.w};
                bw[kk][ct].u4 = pack8(w8);
            }
        float pbv[6];
#pragma unroll
        for (int ct = 0; ct < 6; ++ct) pbv[ct] = gpb[(ct << 4) + r15];
#pragma unroll
        for (int mt = 0; mt < 4; ++mt) {
            const int rowA = (wv << 6) + (mt << 4) + r15;
            FRAG A[3];
#pragma unroll
            for (int kk = 0; kk < 3; ++kk)
                A[kk].u4 = *(const uint4*)(L + FPR0 + rowA * 208 + kk * 64 + (gsl << 4));
            f32x4 acc[6];
#pragma unroll
            for (int ct = 0; ct < 6; ++ct) {
                acc[ct] = __builtin_amdgcn_mfma_f32_16x16x32_bf16(A[0].s8, bw[0][ct].s8, zf, 0, 0, 0);
                acc[ct] = __builtin_amdgcn_mfma_f32_16x16x32_bf16(A[1].s8, bw[1][ct].s8, acc[ct], 0, 0, 0);
                acc[ct] = __builtin_amdgcn_mfma_f32_16x16x32_bf16(A[2].s8, bw[2][ct].s8, acc[ct], 0, 0, 0);
            }
#pragma unroll
            for (int ct = 0; ct < 6; ++ct)
#pragma unroll
                for (int rr = 0; rr < 4; ++rr) {
                    const int token = (wv << 6) + (mt << 4) + (gsl << 2) + rr;
                    const int p = token >> 2, s = token & 3;
                    const int gsq = seq_of(p, s);
                    gout[((size_t)w * 256 + gsq) * 96 + (ct << 4) + r15]
                        = acc[ct][rr] + pbv[ct];
                }
        }
    }
}

extern "C" void kernel_launch(void* const* d_in, const int* in_sizes, int n_in,
                              void* d_out, int out_size, void* d_ws, size_t ws_size,
                              hipStream_t stream) {
    const float* gq     = (const float*)d_in[0];
    const float* gk     = (const float*)d_in[1];
    const float* gv     = (const float*)d_in[2];
    const float* gmask  = (const float*)d_in[3];
    const float* gbt    = (const float*)d_in[4];
    const float* ggamma = (const float*)d_in[5];
    const float* gbeta  = (const float*)d_in[6];
    const float* gpw    = (const float*)d_in[7];
    const float* gpb    = (const float*)d_in[8];
    float* gout = (float*)d_out;

    const int nw  = in_sizes[0] / (256 * 96);
    const int nwm = in_sizes[3] / (64 * 64);
    const size_t comb_bytes = (size_t)nwm * 6 * 4096 * sizeof(float);
    const size_t comb_pad   = (comb_bytes + 255) & ~(size_t)255;
    const size_t pre_bytes  = (size_t)nw * 6 * 256 * 16 * sizeof(__hip_bfloat16);

    if (ws_size >= comb_pad + pre_bytes) {
        float* comb = (float*)d_ws;
        __hip_bfloat16* gpre = (__hip_bfloat16*)((char*)d_ws + comb_pad);
        build_comb<<<nwm * 6, TPB, 0, stream>>>(gmask, gbt, comb);
        dwa_attn<<<nw, TPB, 0, stream>>>(gq, gk, gv, ggamma, gbeta, comb, gpre, nwm);
        dwa_proj<<<nw, TPB, 0, stream>>>(gpre, gpw, gpb, gout);
    } else if (ws_size >= comb_bytes) {
        float* comb = (float*)d_ws;
        build_comb<<<nwm * 6, TPB, 0, stream>>>(gmask, gbt, comb);
        dwa_fused<1><<<nw, TPB, 0, stream>>>(gq, gk, gv, gmask, gbt, ggamma, gbeta,
                                             gpw, gpb, gout, comb, nwm);
    } else {
        dwa_fused<0><<<nw, TPB, 0, stream>>>(gq, gk, gv, gmask, gbt, ggamma, gbeta,
                                             gpw, gpb, gout, (const float*)nullptr, nwm);
    }
}

// Round 9
// 324.182 us; speedup vs baseline: 2.0199x; 2.0199x over previous
//
#include <hip/hip_runtime.h>
#include <hip/hip_bf16.h>

// DiagonalWindowAttention (v7: r7 fused structure, PR moved LDS -> global pre).
//   build_comb : comb[mi][n][q][k] = mask + rel-pos bias (d_ws)
//   dwa_v7     : one block per window, 256 thr, LDS 32.8 KB, LB(256,3):
//                LN+pack q to regs; per head {stage Q/K/VT, QK^T MFMA (C=comb),
//                softmax, PV MFMA, transpose via PRS LDS, coalesced pre store};
//                epilogue: vmcnt drain, proj MFMA from global pre, stores.
//   fallback   : r7 fused kernel (PR in LDS) when ws too small.
//
// token grouping: p = wh*8+ww, s = sh*2+sw, seq g = wh*32+sh*16+ww*2+sw

#define TPB 256

// LDS byte offsets (v7 kernel)
#define Q0   0        // [64][64] bf16 swizzled (8 KB); P overlays after QK^T
#define K0   8192
#define VT0  16384    // V^T per head (8 KB)
#define PRS0 24576    // [2][256][8] bf16 transpose staging (8 KB)
#define V7_LDS 32768

typedef __attribute__((ext_vector_type(8))) short short8;
typedef __attribute__((ext_vector_type(4))) float f32x4;

union FRAG { uint4 u4; short8 s8; unsigned short us[8]; };

__device__ __forceinline__ int seq_of(int p, int s) {
    return ((p >> 3) << 5) | ((s >> 1) << 4) | ((p & 7) << 1) | (s & 1);
}

#define SWZ(row, slot) (((row) << 7) + ((((slot) ^ ((row) & 7))) << 4))

#define LGKM_FENCE() do { \
    asm volatile("s_waitcnt lgkmcnt(0)" ::: "memory"); \
    __builtin_amdgcn_sched_barrier(0); } while (0)

// stage-complete barrier: drain LDS writes, sync; vmcnt stays in flight
#define BAR_STAGE() do { \
    asm volatile("s_waitcnt lgkmcnt(0)" ::: "memory"); \
    __builtin_amdgcn_sched_barrier(0); \
    __builtin_amdgcn_s_barrier(); \
    __builtin_amdgcn_sched_barrier(0); } while (0)

// end-of-iteration barrier: LDS reads already retired via data deps
#define BAR_WAR() do { \
    __builtin_amdgcn_sched_barrier(0); \
    __builtin_amdgcn_s_barrier(); \
    __builtin_amdgcn_sched_barrier(0); } while (0)

__device__ __forceinline__ unsigned short f2b(float x) {
    union { __hip_bfloat16 h; unsigned short u; } z;
    z.h = __float2bfloat16(x);
    return z.u;
}

__device__ __forceinline__ uint4 pack8(const float* v) {
    union { uint4 u4; unsigned short us[8]; } z;
#pragma unroll
    for (int i = 0; i < 8; ++i) z.us[i] = f2b(v[i]);
    return z.u4;
}

__device__ __forceinline__ void load_pack(const float* src, uint4* dst) {
    float v[16];
#pragma unroll
    for (int i = 0; i < 4; ++i) {
        float4 x = ((const float4*)src)[i];
        v[4 * i] = x.x; v[4 * i + 1] = x.y; v[4 * i + 2] = x.z; v[4 * i + 3] = x.w;
    }
    dst[0] = pack8(v);
    dst[1] = pack8(v + 8);
}

// ---------------- pre-kernel: comb = mask + rel-pos bias ----------------
__global__ void build_comb(const float* __restrict__ gmask,
                           const float* __restrict__ gbt,
                           float* __restrict__ comb) {
    const int b = blockIdx.x;            // b = mi*6 + n
    const int mi = b / 6, n = b - mi * 6;
    const int t = threadIdx.x;
    const float* mrow = gmask + (size_t)mi * 4096;
    float* crow = comb + (size_t)b * 4096;
#pragma unroll
    for (int e = 0; e < 4096; e += TPB) {
        const int i = e + t;
        const int q = i >> 6, k = i & 63;
        const int idx = ((q >> 3) - (k >> 3) + 7) * 15 + ((q & 7) - (k & 7) + 7);
        crow[i] = mrow[i] + gbt[idx * 6 + n];
    }
}

// ============================ v7 main kernel ============================
__global__ __launch_bounds__(TPB, 3)
void dwa_v7(const float* __restrict__ gq,
            const float* __restrict__ gk,
            const float* __restrict__ gv,
            const float* __restrict__ ggamma,
            const float* __restrict__ gbeta,
            const float* __restrict__ gpw,
            const float* __restrict__ gpb,
            const float* __restrict__ comb,
            __hip_bfloat16* __restrict__ gpre,
            float* __restrict__ gout,
            int nwm)
{
    __shared__ __align__(16) unsigned char Lraw[V7_LDS];
    char* L = (char*)Lraw;

    const int w = blockIdx.x;
    const int t = threadIdx.x;
    const int lane = t & 63, wv = t >> 6;
    const int r15 = lane & 15, gsl = lane >> 4;

    const int p_a = t >> 2, s_a = t & 3;
    const int g_a = seq_of(p_a, s_a);
    const size_t rowbase = ((size_t)w * 256 + g_a) * 96;
    const int qr0 = (wv << 4) + (gsl << 2);
    const f32x4 zf = {0.f, 0.f, 0.f, 0.f};

    // ---------- phase 0: q full load, LN stats, LN+pack to 12 uint4 ----------
    uint4 qreg[12];
    {
        float qv[96];
        float sum = 0.f, ssq = 0.f;
        const float4* qr4 = (const float4*)(gq + rowbase);
#pragma unroll
        for (int i = 0; i < 24; ++i) {
            float4 x = qr4[i];
            qv[4 * i] = x.x; qv[4 * i + 1] = x.y;
            qv[4 * i + 2] = x.z; qv[4 * i + 3] = x.w;
            sum += (x.x + x.y) + (x.z + x.w);
            ssq += (x.x * x.x + x.y * x.y) + (x.z * x.z + x.w * x.w);
        }
        sum += __shfl_xor(sum, 1); ssq += __shfl_xor(ssq, 1);
        sum += __shfl_xor(sum, 2); ssq += __shfl_xor(ssq, 2);
        const float mu = sum * (1.f / 384.f);
        const float rs = rsqrtf(ssq * (1.f / 384.f) - mu * mu + 1e-5f);
        const float4* ga4 = (const float4*)(ggamma + s_a * 96);
        const float4* be4 = (const float4*)(gbeta + s_a * 96);
#pragma unroll
        for (int c6 = 0; c6 < 6; ++c6) {
            float vals[16];
#pragma unroll
            for (int j = 0; j < 4; ++j) {
                float4 g = ga4[c6 * 4 + j];
                float4 b = be4[c6 * 4 + j];
                const int base = c6 * 16 + 4 * j;
                vals[4 * j + 0] = ((qv[base + 0] - mu) * rs * g.x + b.x) * 0.125f;
                vals[4 * j + 1] = ((qv[base + 1] - mu) * rs * g.y + b.y) * 0.125f;
                vals[4 * j + 2] = ((qv[base + 2] - mu) * rs * g.z + b.z) * 0.125f;
                vals[4 * j + 3] = ((qv[base + 3] - mu) * rs * g.w + b.w) * 0.125f;
            }
            qreg[2 * c6]     = pack8(vals);
            qreg[2 * c6 + 1] = pack8(vals + 8);
        }
    }
    uint4 kpf[2][2], vpf[2][2];
    load_pack(gk + rowbase, kpf[0]);
    load_pack(gv + rowbase, vpf[0]);

    // ----------------------------- head loop -----------------------------
#pragma unroll
    for (int n = 0; n < 6; ++n) {
        // stage Q (regs), K, VT (transposed)
        *(uint4*)(L + Q0 + SWZ(p_a, s_a * 2))     = qreg[2 * n];
        *(uint4*)(L + Q0 + SWZ(p_a, s_a * 2 + 1)) = qreg[2 * n + 1];
        *(uint4*)(L + K0 + SWZ(p_a, s_a * 2))     = kpf[n & 1][0];
        *(uint4*)(L + K0 + SWZ(p_a, s_a * 2 + 1)) = kpf[n & 1][1];
#pragma unroll
        for (int h = 0; h < 2; ++h) {
            FRAG u; u.u4 = vpf[n & 1][h];
#pragma unroll
            for (int c = 0; c < 8; ++c) {
                const int np_ = s_a * 16 + h * 8 + c;
                *(unsigned short*)(L + VT0 + (np_ << 7) +
                    ((((p_a >> 3) ^ (np_ & 7))) << 4) + ((p_a & 7) << 1)) = u.us[c];
            }
        }
        // prefetch next head's k/v
        if (n < 5) {
            load_pack(gk + rowbase + (n + 1) * 16, kpf[(n + 1) & 1]);
            load_pack(gv + rowbase + (n + 1) * 16, vpf[(n + 1) & 1]);
        }
        // C init = comb (bias+mask)
        f32x4 sacc[4];
        {
            const float* cb = comb + (size_t)((w % nwm) * 6 + n) * 4096;
#pragma unroll
            for (int tile = 0; tile < 4; ++tile)
#pragma unroll
                for (int r = 0; r < 4; ++r)
                    sacc[tile][r] = cb[((qr0 + r) << 6) + (tile << 4) + r15];
        }
        BAR_STAGE();

        // QK^T
        {
            FRAG a0, a1;
            a0.u4 = *(const uint4*)(L + Q0 + SWZ(wv * 16 + r15, gsl));
            a1.u4 = *(const uint4*)(L + Q0 + SWZ(wv * 16 + r15, 4 + gsl));
#pragma unroll
            for (int tile = 0; tile < 4; ++tile) {
                FRAG b0, b1;
                b0.u4 = *(const uint4*)(L + K0 + SWZ(tile * 16 + r15, gsl));
                b1.u4 = *(const uint4*)(L + K0 + SWZ(tile * 16 + r15, 4 + gsl));
                sacc[tile] = __builtin_amdgcn_mfma_f32_16x16x32_bf16(a0.s8, b0.s8, sacc[tile], 0, 0, 0);
                sacc[tile] = __builtin_amdgcn_mfma_f32_16x16x32_bf16(a1.s8, b1.s8, sacc[tile], 0, 0, 0);
            }
        }

        // softmax in place; P overlays Q0 (wave-private rows)
#pragma unroll
        for (int r = 0; r < 4; ++r) {
            const int q = qr0 + r;
            float mx = fmaxf(fmaxf(sacc[0][r], sacc[1][r]),
                             fmaxf(sacc[2][r], sacc[3][r]));
            mx = fmaxf(mx, __shfl_xor(mx, 1));
            mx = fmaxf(mx, __shfl_xor(mx, 2));
            mx = fmaxf(mx, __shfl_xor(mx, 4));
            mx = fmaxf(mx, __shfl_xor(mx, 8));
            float sm = 0.f;
#pragma unroll
            for (int tile = 0; tile < 4; ++tile) {
                sacc[tile][r] = __expf(sacc[tile][r] - mx);
                sm += sacc[tile][r];
            }
            sm += __shfl_xor(sm, 1);
            sm += __shfl_xor(sm, 2);
            sm += __shfl_xor(sm, 4);
            sm += __shfl_xor(sm, 8);
            const float inv = 1.0f / sm;
#pragma unroll
            for (int tile = 0; tile < 4; ++tile) {
                const int col = (tile << 4) + r15;
                *(unsigned short*)(L + Q0 + (q << 7) +
                                   (((col >> 3) ^ (q & 7)) << 4) + ((col & 7) << 1))
                    = f2b(sacc[tile][r] * inv);
            }
        }
        LGKM_FENCE();

        // PV
        f32x4 oacc[4];
        {
            FRAG pa0, pa1;
            pa0.u4 = *(const uint4*)(L + Q0 + SWZ(wv * 16 + r15, gsl));
            pa1.u4 = *(const uint4*)(L + Q0 + SWZ(wv * 16 + r15, 4 + gsl));
#pragma unroll
            for (int ct = 0; ct < 4; ++ct) {
                FRAG b0, b1;
                b0.u4 = *(const uint4*)(L + VT0 + SWZ(ct * 16 + r15, gsl));
                b1.u4 = *(const uint4*)(L + VT0 + SWZ(ct * 16 + r15, 4 + gsl));
                oacc[ct] = __builtin_amdgcn_mfma_f32_16x16x32_bf16(pa0.s8, b0.s8, zf, 0, 0, 0);
                oacc[ct] = __builtin_amdgcn_mfma_f32_16x16x32_bf16(pa1.s8, b1.s8, oacc[ct], 0, 0, 0);
            }
        }

        // transpose via PRS: [h=r15>>3][tok][r15&7] (wave-private rows)
#pragma unroll
        for (int ct = 0; ct < 4; ++ct)
#pragma unroll
            for (int r = 0; r < 4; ++r) {
                const int tok = ((qr0 + r) << 2) + ct;
                *(unsigned short*)(L + PRS0 + ((r15 >> 3) << 12) + (tok << 4) +
                                   ((r15 & 7) << 1)) = f2b(oacc[ct][r]);
            }
        LGKM_FENCE();
        // coalesced pre store: thread t owns token t (same wave's rows)
        {
            uint4 lo = *(const uint4*)(L + PRS0 + (t << 4));
            uint4 hi = *(const uint4*)(L + PRS0 + 4096 + (t << 4));
            unsigned short* pb = (unsigned short*)gpre + (((size_t)w * 6 + n) << 12) + (t << 4);
            *(uint4*)(pb)     = lo;
            *(uint4*)(pb + 8) = hi;
        }
        BAR_WAR();
    }

    // ---------------- epilogue: projection from global pre ----------------
    asm volatile("s_waitcnt vmcnt(0)" ::: "memory");
    __builtin_amdgcn_sched_barrier(0);
    {
        FRAG bw[3][6];
#pragma unroll
        for (int kk = 0; kk < 3; ++kk)
#pragma unroll
            for (int ct = 0; ct < 6; ++ct) {
                const int o = (ct << 4) + r15;
                const float4* wp = (const float4*)(gpw + o * 96 + kk * 32 + (gsl << 3));
                float4 w0 = wp[0], w1 = wp[1];
                float w8[8] = {w0.x, w0.y, w0.z, w0.w, w1.x, w1.y, w1.z, w1.w};
                bw[kk][ct].u4 = pack8(w8);
            }
        float pbv[6];
#pragma unroll
        for (int ct = 0; ct < 6; ++ct) pbv[ct] = gpb[(ct << 4) + r15];

#pragma unroll
        for (int mt = 0; mt < 4; ++mt) {
            const int rowA = (wv << 6) + (mt << 4) + r15;
            FRAG A[3];
#pragma unroll
            for (int kk = 0; kk < 3; ++kk) {
                const int n = kk * 2 + (gsl >> 1);
                const int c0 = (gsl & 1) << 3;
                A[kk].u4 = *(const uint4*)((const unsigned short*)gpre +
                                           (((size_t)w * 6 + n) << 12) + (rowA << 4) + c0);
            }
            f32x4 acc[6];
#pragma unroll
            for (int ct = 0; ct < 6; ++ct) {
                acc[ct] = __builtin_amdgcn_mfma_f32_16x16x32_bf16(A[0].s8, bw[0][ct].s8, zf, 0, 0, 0);
                acc[ct] = __builtin_amdgcn_mfma_f32_16x16x32_bf16(A[1].s8, bw[1][ct].s8, acc[ct], 0, 0, 0);
                acc[ct] = __builtin_amdgcn_mfma_f32_16x16x32_bf16(A[2].s8, bw[2][ct].s8, acc[ct], 0, 0, 0);
            }
#pragma unroll
            for (int ct = 0; ct < 6; ++ct)
#pragma unroll
                for (int rr = 0; rr < 4; ++rr) {
                    const int token = (wv << 6) + (mt << 4) + (gsl << 2) + rr;
                    const int p = token >> 2, s = token & 3;
                    const int gsq = seq_of(p, s);
                    gout[((size_t)w * 256 + gsq) * 96 + (ct << 4) + r15]
                        = acc[ct][rr] + pbv[ct];
                }
        }
    }
}

// ======================= fallback: r7 fused kernel =======================
#define FQ0   0
#define FK0   8192
#define FVT0  16384
#define FPR0  24576
#define F_LDS 77824

template <int USE_COMB>
__global__ __launch_bounds__(TPB, 2)
void dwa_fused(const float* __restrict__ gq,
               const float* __restrict__ gk,
               const float* __restrict__ gv,
               const float* __restrict__ gmask,
               const float* __restrict__ gbt,
               const float* __restrict__ ggamma,
               const float* __restrict__ gbeta,
               const float* __restrict__ gpw,
               const float* __restrict__ gpb,
               float* __restrict__ gout,
               const float* __restrict__ comb,
               int nwm)
{
    __shared__ __align__(16) unsigned char Lraw[F_LDS];
    char* L = (char*)Lraw;

    const int w = blockIdx.x;
    const int t = threadIdx.x;
    const int lane = t & 63, wv = t >> 6;
    const int r15 = lane & 15, gsl = lane >> 4;

    const int p_a = t >> 2, s_a = t & 3;
    const int g_a = seq_of(p_a, s_a);
    const size_t rowbase = ((size_t)w * 256 + g_a) * 96;
    const int mbase = (w % nwm) * 4096;
    const int qr0 = (wv << 4) + (gsl << 2);
    const f32x4 zf = {0.f, 0.f, 0.f, 0.f};

    uint4 qreg[12];
    {
        float qv[96];
        float sum = 0.f, ssq = 0.f;
        const float4* qr4 = (const float4*)(gq + rowbase);
#pragma unroll
        for (int i = 0; i < 24; ++i) {
            float4 x = qr4[i];
            qv[4 * i] = x.x; qv[4 * i + 1] = x.y;
            qv[4 * i + 2] = x.z; qv[4 * i + 3] = x.w;
            sum += (x.x + x.y) + (x.z + x.w);
            ssq += (x.x * x.x + x.y * x.y) + (x.z * x.z + x.w * x.w);
        }
        sum += __shfl_xor(sum, 1); ssq += __shfl_xor(ssq, 1);
        sum += __shfl_xor(sum, 2); ssq += __shfl_xor(ssq, 2);
        const float mu = sum * (1.f / 384.f);
        const float rs = rsqrtf(ssq * (1.f / 384.f) - mu * mu + 1e-5f);
        const float4* ga4 = (const float4*)(ggamma + s_a * 96);
        const float4* be4 = (const float4*)(gbeta + s_a * 96);
#pragma unroll
        for (int c6 = 0; c6 < 6; ++c6) {
            float vals[16];
#pragma unroll
            for (int j = 0; j < 4; ++j) {
                float4 g = ga4[c6 * 4 + j];
                float4 b = be4[c6 * 4 + j];
                const int base = c6 * 16 + 4 * j;
                vals[4 * j + 0] = ((qv[base + 0] - mu) * rs * g.x + b.x) * 0.125f;
                vals[4 * j + 1] = ((qv[base + 1] - mu) * rs * g.y + b.y) * 0.125f;
                vals[4 * j + 2] = ((qv[base + 2] - mu) * rs * g.z + b.z) * 0.125f;
                vals[4 * j + 3] = ((qv[base + 3] - mu) * rs * g.w + b.w) * 0.125f;
            }
            qreg[2 * c6]     = pack8(vals);
            qreg[2 * c6 + 1] = pack8(vals + 8);
        }
    }
    uint4 kpf[2][2], vpf[2][2];
    load_pack(gk + rowbase, kpf[0]);
    load_pack(gv + rowbase, vpf[0]);

#pragma unroll
    for (int n = 0; n < 6; ++n) {
        *(uint4*)(L + FQ0 + SWZ(p_a, s_a * 2))     = qreg[2 * n];
        *(uint4*)(L + FQ0 + SWZ(p_a, s_a * 2 + 1)) = qreg[2 * n + 1];
        *(uint4*)(L + FK0 + SWZ(p_a, s_a * 2))     = kpf[n & 1][0];
        *(uint4*)(L + FK0 + SWZ(p_a, s_a * 2 + 1)) = kpf[n & 1][1];
#pragma unroll
        for (int h = 0; h < 2; ++h) {
            FRAG u; u.u4 = vpf[n & 1][h];
#pragma unroll
            for (int c = 0; c < 8; ++c) {
                const int np_ = s_a * 16 + h * 8 + c;
                *(unsigned short*)(L + FVT0 + (np_ << 7) +
                    ((((p_a >> 3) ^ (np_ & 7))) << 4) + ((p_a & 7) << 1)) = u.us[c];
            }
        }
        if (n < 5) {
            load_pack(gk + rowbase + (n + 1) * 16, kpf[(n + 1) & 1]);
            load_pack(gv + rowbase + (n + 1) * 16, vpf[(n + 1) & 1]);
        }
        f32x4 sacc[4];
        if (USE_COMB) {
            const float* cb = comb + (size_t)((w % nwm) * 6 + n) * 4096;
#pragma unroll
            for (int tile = 0; tile < 4; ++tile)
#pragma unroll
                for (int r = 0; r < 4; ++r)
                    sacc[tile][r] = cb[((qr0 + r) << 6) + (tile << 4) + r15];
        } else {
#pragma unroll
            for (int tile = 0; tile < 4; ++tile) {
                const int kpx = (tile << 4) + r15;
                const int ik = kpx >> 3, jk = kpx & 7;
#pragma unroll
                for (int r = 0; r < 4; ++r) {
                    const int q = qr0 + r;
                    sacc[tile][r] = gbt[(((q >> 3) - ik + 7) * 15 + ((q & 7) - jk + 7)) * 6 + n]
                                  + gmask[mbase + (q << 6) + kpx];
                }
            }
        }
        __syncthreads();
        {
            FRAG a0, a1;
            a0.u4 = *(const uint4*)(L + FQ0 + SWZ(wv * 16 + r15, gsl));
            a1.u4 = *(const uint4*)(L + FQ0 + SWZ(wv * 16 + r15, 4 + gsl));
#pragma unroll
            for (int tile = 0; tile < 4; ++tile) {
                FRAG b0, b1;
                b0.u4 = *(const uint4*)(L + FK0 + SWZ(tile * 16 + r15, gsl));
                b1.u4 = *(const uint4*)(L + FK0 + SWZ(tile * 16 + r15, 4 + gsl));
                sacc[tile] = __builtin_amdgcn_mfma_f32_16x16x32_bf16(a0.s8, b0.s8, sacc[tile], 0, 0, 0);
                sacc[tile] = __builtin_amdgcn_mfma_f32_16x16x32_bf16(a1.s8, b1.s8, sacc[tile], 0, 0, 0);
            }
        }
#pragma unroll
        for (int r = 0; r < 4; ++r) {
            const int q = qr0 + r;
            float mx = fmaxf(fmaxf(sacc[0][r], sacc[1][r]),
                             fmaxf(sacc[2][r], sacc[3][r]));
            mx = fmaxf(mx, __shfl_xor(mx, 1));
            mx = fmaxf(mx, __shfl_xor(mx, 2));
            mx = fmaxf(mx, __shfl_xor(mx, 4));
            mx = fmaxf(mx, __shfl_xor(mx, 8));
            float sm = 0.f;
#pragma unroll
            for (int tile = 0; tile < 4; ++tile) {
                sacc[tile][r] = __expf(sacc[tile][r] - mx);
                sm += sacc[tile][r];
            }
            sm += __shfl_xor(sm, 1);
            sm += __shfl_xor(sm, 2);
            sm += __shfl_xor(sm, 4);
            sm += __shfl_xor(sm, 8);
            const float inv = 1.0f / sm;
#pragma unroll
            for (int tile = 0; tile < 4; ++tile) {
                const int col = (tile << 4) + r15;
                *(unsigned short*)(L + FQ0 + (q << 7) +
                                   (((col >> 3) ^ (q & 7)) << 4) + ((col & 7) << 1))
                    = f2b(sacc[tile][r] * inv);
            }
        }
        LGKM_FENCE();
        f32x4 oacc[4];
        {
            FRAG pa0, pa1;
            pa0.u4 = *(const uint4*)(L + FQ0 + SWZ(wv * 16 + r15, gsl));
            pa1.u4 = *(const uint4*)(L + FQ0 + SWZ(wv * 16 + r15, 4 + gsl));
#pragma unroll
            for (int ct = 0; ct < 4; ++ct) {
                FRAG b0, b1;
                b0.u4 = *(const uint4*)(L + FVT0 + SWZ(ct * 16 + r15, gsl));
                b1.u4 = *(const uint4*)(L + FVT0 + SWZ(ct * 16 + r15, 4 + gsl));
                oacc[ct] = __builtin_amdgcn_mfma_f32_16x16x32_bf16(pa0.s8, b0.s8, zf, 0, 0, 0);
                oacc[ct] = __builtin_amdgcn_mfma_f32_16x16x32_bf16(pa1.s8, b1.s8, oacc[ct], 0, 0, 0);
            }
        }
#pragma unroll
        for (int ct = 0; ct < 4; ++ct)
#pragma unroll
            for (int r = 0; r < 4; ++r) {
                const int token = ((qr0 + r) << 2) + ct;
                *(unsigned short*)(L + FPR0 + token * 208 + ((n << 4) + r15) * 2)
                    = f2b(oacc[ct][r]);
            }
        __syncthreads();
    }
    {
        FRAG bw[3][6];
#pragma unroll
        for (int kk = 0; kk < 3; ++kk)
#pragma unroll
            for (int ct = 0; ct < 6; ++ct) {
                const int o = (ct << 4) + r15;
                const float4* wp = (const float4*)(gpw + o * 96 + kk * 32 + (gsl << 3));
                float4 w0 = wp[0], w1 = wp[1];
                float w8[8] = {w0.x, w0.y, w0.z, w0.w, w1.x, w1.y, w1.z, w1.w};
                bw[kk][ct].u4 = pack8(w8);
            }
        float pbv[6];
#pragma unroll
        for (int ct = 0; ct < 6; ++ct) pbv[ct] = gpb[(ct << 4) + r15];
#pragma unroll
        for (int mt = 0; mt < 4; ++mt) {
            const int rowA = (wv << 6) + (mt << 4) + r15;
            FRAG A[3];
#pragma unroll
            for (int kk = 0; kk < 3; ++kk)
                A[kk].u4 = *(const uint4*)(L + FPR0 + rowA * 208 + kk * 64 + (gsl << 4));
            f32x4 acc[6];
#pragma unroll
            for (int ct = 0; ct < 6; ++ct) {
                acc[ct] = __builtin_amdgcn_mfma_f32_16x16x32_bf16(A[0].s8, bw[0][ct].s8, zf, 0, 0, 0);
                acc[ct] = __builtin_amdgcn_mfma_f32_16x16x32_bf16(A[1].s8, bw[1][ct].s8, acc[ct], 0, 0, 0);
                acc[ct] = __builtin_amdgcn_mfma_f32_16x16x32_bf16(A[2].s8, bw[2][ct].s8, acc[ct], 0, 0, 0);
            }
#pragma unroll
            for (int ct = 0; ct < 6; ++ct)
#pragma unroll
                for (int rr = 0; rr < 4; ++rr) {
                    const int token = (wv << 6) + (mt << 4) + (gsl << 2) + rr;
                    const int p = token >> 2, s = token & 3;
                    const int gsq = seq_of(p, s);
                    gout[((size_t)w * 256 + gsq) * 96 + (ct << 4) + r15]
                        = acc[ct][rr] + pbv[ct];
                }
        }
    }
}

extern "C" void kernel_launch(void* const* d_in, const int* in_sizes, int n_in,
                              void* d_out, int out_size, void* d_ws, size_t ws_size,
                              hipStream_t stream) {
    const float* gq     = (const float*)d_in[0];
    const float* gk     = (const float*)d_in[1];
    const float* gv     = (const float*)d_in[2];
    const float* gmask  = (const float*)d_in[3];
    const float* gbt    = (const float*)d_in[4];
    const float* ggamma = (const float*)d_in[5];
    const float* gbeta  = (const float*)d_in[6];
    const float* gpw    = (const float*)d_in[7];
    const float* gpb    = (const float*)d_in[8];
    float* gout = (float*)d_out;

    const int nw  = in_sizes[0] / (256 * 96);
    const int nwm = in_sizes[3] / (64 * 64);
    const size_t comb_bytes = (size_t)nwm * 6 * 4096 * sizeof(float);
    const size_t comb_pad   = (comb_bytes + 255) & ~(size_t)255;
    const size_t pre_bytes  = (size_t)nw * 6 * 256 * 16 * sizeof(__hip_bfloat16);

    if (ws_size >= comb_pad + pre_bytes) {
        float* comb = (float*)d_ws;
        __hip_bfloat16* gpre = (__hip_bfloat16*)((char*)d_ws + comb_pad);
        build_comb<<<nwm * 6, TPB, 0, stream>>>(gmask, gbt, comb);
        dwa_v7<<<nw, TPB, 0, stream>>>(gq, gk, gv, ggamma, gbeta, gpw, gpb,
                                       comb, gpre, gout, nwm);
    } else if (ws_size >= comb_bytes) {
        float* comb = (float*)d_ws;
        build_comb<<<nwm * 6, TPB, 0, stream>>>(gmask, gbt, comb);
        dwa_fused<1><<<nw, TPB, 0, stream>>>(gq, gk, gv, gmask, gbt, ggamma, gbeta,
                                             gpw, gpb, gout, comb, nwm);
    } else {
        dwa_fused<0><<<nw, TPB, 0, stream>>>(gq, gk, gv, gmask, gbt, ggamma, gbeta,
                                             gpw, gpb, gout, (const float*)nullptr, nwm);
    }
}